// Round 3
// baseline (1905.586 us; speedup 1.0000x reference)
//
#include <hip/hip_runtime.h>
#include <cstdint>

#define NUM_HEADS 32
#define HEAD 80
#define DQK 104   // padded head-dim stride for q/k
#define HID 2560
#define H3 7680
#define H4 10240
#define NA 17920  // fused QKV+FC1 output width
#define KB 12800  // fused outproj+FC2 K (2560 + 10240)
#define BB 2
#define SS 2048
#define ROWS (BB*SS)  // 4096

typedef __bf16 bf16_t;
typedef __bf16 bf16x8 __attribute__((ext_vector_type(8)));
typedef __bf16 bf16x4 __attribute__((ext_vector_type(4)));
typedef float  f32x4  __attribute__((ext_vector_type(4)));

typedef __attribute__((address_space(1))) void* gptr_t;
typedef __attribute__((address_space(3))) void* lptr_t;

__device__ __forceinline__ void async_copy16(const void* g, void* l) {
  __builtin_amdgcn_global_load_lds((gptr_t)g, (lptr_t)l, 16, 0, 0);
}

// ---------------------------------------------------------------------------
// Weight fp32 [K][N] -> bf16 [N][K] transpose+convert, 64x64 tiles,
// float4 global loads, bf16x4 stores, strided destination (ldt).
// ---------------------------------------------------------------------------
__global__ __launch_bounds__(256) void wconv64(const float* __restrict__ W,
                                               bf16_t* __restrict__ Wt,
                                               int K, int N, int ldt) {
  __shared__ float t[64][65];
  const int n0 = blockIdx.x * 64, k0 = blockIdx.y * 64;
  const int tx = threadIdx.x & 15, ty = threadIdx.x >> 4;
#pragma unroll
  for (int i = 0; i < 4; i++) {
    const int row = ty + 16 * i;
    float4 v = *(const float4*)(W + (size_t)(k0 + row) * N + n0 + tx * 4);
    t[row][tx * 4 + 0] = v.x;
    t[row][tx * 4 + 1] = v.y;
    t[row][tx * 4 + 2] = v.z;
    t[row][tx * 4 + 3] = v.w;
  }
  __syncthreads();
#pragma unroll
  for (int i = 0; i < 4; i++) {
    const int n = ty + 16 * i;
    bf16x4 o;
#pragma unroll
    for (int j = 0; j < 4; j++) o[j] = (bf16_t)t[tx * 4 + j][n];
    *(bf16x4*)(Wt + (size_t)(n0 + n) * ldt + k0 + tx * 4) = o;
  }
}

// ---------------------------------------------------------------------------
// LayerNorm: fp32 [4096][2560] -> bf16 [4096][2560]
// ---------------------------------------------------------------------------
__global__ __launch_bounds__(256) void ln_kernel(const float* __restrict__ x,
                                                 const float* __restrict__ w,
                                                 const float* __restrict__ b,
                                                 bf16_t* __restrict__ o) {
  const int row = blockIdx.x;
  const int tid = threadIdx.x;
  const int wid = tid >> 6, lane = tid & 63;
  const float4* xr = (const float4*)(x + (size_t)row * HID);
  __shared__ float red[8];

  float4 vals[3];
  int nc = 0;
  float s = 0.f;
  for (int c = tid; c < HID / 4; c += 256) {
    float4 v = xr[c];
    vals[nc++] = v;
    s += v.x + v.y + v.z + v.w;
  }
#pragma unroll
  for (int o2 = 32; o2 > 0; o2 >>= 1) s += __shfl_down(s, o2);
  if (lane == 0) red[wid] = s;
  __syncthreads();
  const float mean = (red[0] + red[1] + red[2] + red[3]) * (1.f / HID);

  float s2 = 0.f;
  nc = 0;
  for (int c = tid; c < HID / 4; c += 256) {
    float4 v = vals[nc++];
    float a0 = v.x - mean, a1 = v.y - mean, a2 = v.z - mean, a3 = v.w - mean;
    s2 += a0 * a0 + a1 * a1 + a2 * a2 + a3 * a3;
  }
#pragma unroll
  for (int o2 = 32; o2 > 0; o2 >>= 1) s2 += __shfl_down(s2, o2);
  __syncthreads();
  if (lane == 0) red[4 + wid] = s2;
  __syncthreads();
  const float var = (red[4] + red[5] + red[6] + red[7]) * (1.f / HID);
  const float rstd = rsqrtf(var + 1e-5f);

  bf16_t* orow = o + (size_t)row * HID;
  nc = 0;
  for (int c = tid; c < HID / 4; c += 256) {
    float4 v = vals[nc++];
    float4 wv = ((const float4*)w)[c];
    float4 bv = ((const float4*)b)[c];
    bf16x4 r4;
    r4[0] = (bf16_t)((v.x - mean) * rstd * wv.x + bv.x);
    r4[1] = (bf16_t)((v.y - mean) * rstd * wv.y + bv.y);
    r4[2] = (bf16_t)((v.z - mean) * rstd * wv.z + bv.z);
    r4[3] = (bf16_t)((v.w - mean) * rstd * wv.w + bv.w);
    *(bf16x4*)(orow + c * 4) = r4;
  }
}

// ---------------------------------------------------------------------------
// bf16 GEMM, A [M][K] (stride K), Bt [N][K] (stride K), 128x128x32 tiles.
// Block-id remapped M-major so consecutive blocks share a B-panel (L2 reuse).
// MODE 0 (fused QKV+FC1): n<7680 -> q(104,pre-scaled)/k(104)/v(transposed+
//   swizzled) scatter (+qkvb); n>=7680 -> fast-gelu(+fc1b) -> U[:,2560+j].
// MODE 1 (fused outproj+FC2 final): out = acc + hid + b0[n] + b1[n].
// ---------------------------------------------------------------------------
template <int MODE>
__global__ __launch_bounds__(256) void gemm_bt(
    const bf16_t* __restrict__ A, const bf16_t* __restrict__ Bt,
    int M, int N, int K,
    const float* __restrict__ b0, const float* __restrict__ b1,
    const float* __restrict__ hid, float* __restrict__ outF,
    bf16_t* __restrict__ U,
    bf16_t* __restrict__ qp, bf16_t* __restrict__ kp, bf16_t* __restrict__ vt) {
  __shared__ bf16_t Ash[128 * 32];
  __shared__ bf16_t Bsh[128 * 32];
  const int tid = threadIdx.x;
  const int wid = tid >> 6, lane = tid & 63;
  const int wrow = wid >> 1, wcol = wid & 1;
  const int lr = lane & 15, lq = lane >> 4;
  const int Mb = M >> 7;
  const int bid = blockIdx.x + blockIdx.y * gridDim.x;
  const int m0 = (bid % Mb) * 128;
  const int n0 = (bid / Mb) * 128;
  const bf16_t* Ab = A + (size_t)m0 * K;
  const bf16_t* Bb = Bt + (size_t)n0 * K;
  const int srow = wid * 16 + (lane >> 2);
  const int sk = (lane & 3) * 8;

  f32x4 acc[4][4] = {};

  for (int kt = 0; kt < K; kt += 32) {
    __syncthreads();
    async_copy16(Ab + (size_t)srow * K + kt + sk, &Ash[srow * 32 + sk]);
    async_copy16(Ab + (size_t)(srow + 64) * K + kt + sk, &Ash[(srow + 64) * 32 + sk]);
    async_copy16(Bb + (size_t)srow * K + kt + sk, &Bsh[srow * 32 + sk]);
    async_copy16(Bb + (size_t)(srow + 64) * K + kt + sk, &Bsh[(srow + 64) * 32 + sk]);
    __syncthreads();
    bf16x8 af[4], bfr[4];
#pragma unroll
    for (int mi = 0; mi < 4; mi++)
      af[mi] = *(const bf16x8*)&Ash[(wrow * 64 + mi * 16 + lr) * 32 + lq * 8];
#pragma unroll
    for (int ni = 0; ni < 4; ni++)
      bfr[ni] = *(const bf16x8*)&Bsh[(wcol * 64 + ni * 16 + lr) * 32 + lq * 8];
#pragma unroll
    for (int mi = 0; mi < 4; mi++)
#pragma unroll
      for (int ni = 0; ni < 4; ni++)
        acc[mi][ni] = __builtin_amdgcn_mfma_f32_16x16x32_bf16(af[mi], bfr[ni], acc[mi][ni], 0, 0, 0);
  }

  // C/D layout: col = lane&15 (n), row = (lane>>4)*4 + r (m)
  if constexpr (MODE == 0) {
    if (n0 < H3) {
      // ---- QKV scatter ----
#pragma unroll
      for (int ni = 0; ni < 4; ni++) {
        const int n = n0 + wcol * 64 + ni * 16 + lr;
        const float bn = b0[n];
        const int which = n / HID;
        const int wi = n - which * HID;
        const int hh = wi / HEAD;
        const int dd = wi - hh * HEAD;
#pragma unroll
        for (int mi = 0; mi < 4; mi++) {
#pragma unroll
          for (int r = 0; r < 4; r++) {
            const int m = m0 + wrow * 64 + mi * 16 + lq * 4 + r;
            const int bb2 = m >> 11, ss2 = m & (SS - 1);
            const size_t bh = (size_t)(bb2 * NUM_HEADS + hh);
            float v = acc[mi][ni][r] + bn;
            if (which == 0) {
              // pre-scale Q by 1/sqrt(80)*log2(e); commutes with RoPE
              qp[(bh * SS + ss2) * DQK + dd] = (bf16_t)(v * 0.16129822f);
            } else if (which == 1) {
              kp[(bh * SS + ss2) * DQK + dd] = (bf16_t)v;
            } else {
              // transposed + XOR-8 chunk-swizzled V: [bh][dd][s]
              const int sblk = ss2 & ~63;
              const int pch = ((ss2 >> 3) & 7) ^ (dd & 7);
              vt[(bh * HEAD + dd) * SS + sblk + pch * 8 + (ss2 & 7)] = (bf16_t)v;
            }
          }
        }
      }
    } else {
      // ---- FC1 + fast-gelu -> U[:, 2560+j] ----
#pragma unroll
      for (int ni = 0; ni < 4; ni++) {
        const int n = n0 + wcol * 64 + ni * 16 + lr;
        const int j = n - H3;
        const float bn = b1[j];
#pragma unroll
        for (int mi = 0; mi < 4; mi++) {
#pragma unroll
          for (int r = 0; r < 4; r++) {
            const int m = m0 + wrow * 64 + mi * 16 + lq * 4 + r;
            float v = acc[mi][ni][r] + bn;
            const float y = 0.7978845608f * (v + 0.044715f * v * v * v);
            const float a = fabsf(y);
            const float e = exp2f(-2.885390082f * a);
            float t = (1.f - e) * __builtin_amdgcn_rcpf(1.f + e);
            t = copysignf(t, y);
            U[(size_t)m * KB + HID + j] = (bf16_t)(0.5f * v * (1.f + t));
          }
        }
      }
    }
  } else {
#pragma unroll
    for (int mi = 0; mi < 4; mi++) {
#pragma unroll
      for (int ni = 0; ni < 4; ni++) {
        const int n = n0 + wcol * 64 + ni * 16 + lr;
        const float bn = b0[n] + b1[n];
#pragma unroll
        for (int r = 0; r < 4; r++) {
          const int m = m0 + wrow * 64 + mi * 16 + lq * 4 + r;
          const size_t idx = (size_t)m * N + n;
          outF[idx] = acc[mi][ni][r] + hid[idx] + bn;
        }
      }
    }
  }
}

// ---------------------------------------------------------------------------
// Partial RoPE on q/k (104-stride), first 32 dims (half=16). Rotation only.
// ---------------------------------------------------------------------------
__global__ __launch_bounds__(256) void rope_kernel(bf16_t* __restrict__ qp,
                                                   bf16_t* __restrict__ kp) {
  const int idx = blockIdx.x * 256 + threadIdx.x;
  const int d = idx & 15;
  const int bhs = (idx >> 4) & (BB * NUM_HEADS * SS - 1);
  const int isk = idx >> 21;
  bf16_t* base = (isk ? kp : qp) + (size_t)bhs * DQK;
  const int s = bhs & (SS - 1);
  const float fr = exp2f((float)d * -0.830482024f);  // 10000^(-d/16)
  const float ang = (float)s * fr;
  float sn, cs;
  sincosf(ang, &sn, &cs);
  const float x1 = (float)base[d];
  const float x2 = (float)base[d + 16];
  base[d] = (bf16_t)(x1 * cs - x2 * sn);
  base[d + 16] = (bf16_t)(x1 * sn + x2 * cs);
}

// ---------------------------------------------------------------------------
// Causal flash attention, no-max-subtraction softmax (Q pre-scaled by
// log2e/sqrt(80)). Block = 64 q-rows, 4 waves x 16 rows; 64-key tiles.
// Output written into U[:, 0:2560) with row stride 12800.
// ---------------------------------------------------------------------------
__global__ __launch_bounds__(256, 3) void attn_kernel(
    const bf16_t* __restrict__ qb, const bf16_t* __restrict__ kb,
    const bf16_t* __restrict__ vt, bf16_t* __restrict__ U) {
  __shared__ bf16_t Qs[64 * DQK];
  __shared__ bf16_t Ks[64 * DQK];
  __shared__ bf16_t Vs[80 * 64];     // [d][key], XOR-8 chunk-swizzled rows
  __shared__ bf16_t Ps[4][16 * 72];

  const int tid = threadIdx.x;
  const int wid = tid >> 6, lane = tid & 63;
  const int lr = lane & 15, lq = lane >> 4;
  const int b = blockIdx.z, h = blockIdx.y;
  const int qt = (int)gridDim.x - 1 - (int)blockIdx.x;  // heavy tiles first
  const int q0 = qt * 64;
  const size_t hoff = (size_t)(b * NUM_HEADS + h) * SS;
  const bf16_t* Qg = qb + hoff * DQK + (size_t)q0 * DQK;
  const bf16_t* Kg = kb + hoff * DQK;
  const bf16_t* Vg = vt + hoff * HEAD;  // [d][s]

#pragma unroll
  for (int i = 0; i < 3; i++) {
    const int cc = i * 256 + tid;
    async_copy16(Qg + cc * 8, &Qs[cc * 8]);
  }
  if (tid < 64) {
    const int cc = 768 + tid;
    async_copy16(Qg + cc * 8, &Qs[cc * 8]);
  }

  f32x4 oacc[5] = {};
  float lsum[4] = {0.f, 0.f, 0.f, 0.f};
  const int row_base = q0 + wid * 16 + lq * 4;
  const int nkt = qt + 1;

  for (int kt = 0; kt < nkt; kt++) {
    const int k0 = kt * 64;
    __syncthreads();
#pragma unroll
    for (int i = 0; i < 3; i++) {
      const int cc = i * 256 + tid;
      async_copy16(Kg + (size_t)k0 * DQK + cc * 8, &Ks[cc * 8]);
    }
    if (tid < 64) {
      const int cc = 768 + tid;
      async_copy16(Kg + (size_t)k0 * DQK + cc * 8, &Ks[cc * 8]);
    }
#pragma unroll
    for (int i = 0; i < 2; i++) {
      const int c = i * 256 + tid;
      const int d = c >> 3, p = c & 7;
      async_copy16(Vg + (size_t)d * SS + k0 + p * 8, &Vs[c * 8]);
    }
    if (tid < 128) {
      const int c = 512 + tid;
      const int d = c >> 3, p = c & 7;
      async_copy16(Vg + (size_t)d * SS + k0 + p * 8, &Vs[c * 8]);
    }
    __syncthreads();

    f32x4 sacc[4] = {};
#pragma unroll
    for (int kk = 0; kk < 3; kk++) {
      bf16x8 af = *(const bf16x8*)&Qs[(wid * 16 + lr) * DQK + kk * 32 + lq * 8];
#pragma unroll
      for (int ni = 0; ni < 4; ni++) {
        bf16x8 bfr = *(const bf16x8*)&Ks[(ni * 16 + lr) * DQK + kk * 32 + lq * 8];
        sacc[ni] = __builtin_amdgcn_mfma_f32_16x16x32_bf16(af, bfr, sacc[ni], 0, 0, 0);
      }
    }

    const bool last = (kt == nkt - 1);
#pragma unroll
    for (int r = 0; r < 4; r++) {
#pragma unroll
      for (int ni = 0; ni < 4; ni++) {
        float p = exp2f(sacc[ni][r]);
        if (last && (k0 + ni * 16 + lr) > (row_base + r)) p = 0.f;
        lsum[r] += p;
        Ps[wid][(lq * 4 + r) * 72 + ni * 16 + lr] = (bf16_t)p;
      }
    }
    __builtin_amdgcn_s_waitcnt(0xc07f);  // lgkmcnt(0): own-wave Ps visible

#pragma unroll
    for (int kk = 0; kk < 2; kk++) {
      bf16x8 pf = *(const bf16x8*)&Ps[wid][lr * 72 + kk * 32 + lq * 8];
#pragma unroll
      for (int di = 0; di < 5; di++) {
        const int d = di * 16 + lr;
        bf16x8 vf = *(const bf16x8*)&Vs[d * 64 + (((kk * 4 + lq) ^ (d & 7)) * 8)];
        oacc[di] = __builtin_amdgcn_mfma_f32_16x16x32_bf16(pf, vf, oacc[di], 0, 0, 0);
      }
    }
  }

#pragma unroll
  for (int r = 0; r < 4; r++) {
    float l = lsum[r];
    l += __shfl_xor(l, 1);
    l += __shfl_xor(l, 2);
    l += __shfl_xor(l, 4);
    l += __shfl_xor(l, 8);
    const float inv = 1.f / l;
    const int rowg = row_base + r;
    bf16_t* orow = U + (size_t)(b * SS + rowg) * KB + h * HEAD;
#pragma unroll
    for (int di = 0; di < 5; di++)
      orow[di * 16 + lr] = (bf16_t)(oacc[di][r] * inv);
  }
}

// ---------------------------------------------------------------------------
extern "C" void kernel_launch(void* const* d_in, const int* in_sizes, int n_in,
                              void* d_out, int out_size, void* d_ws, size_t ws_size,
                              hipStream_t stream) {
  const float* hid  = (const float*)d_in[0];
  const float* lnw  = (const float*)d_in[1];
  const float* lnb  = (const float*)d_in[2];
  const float* qkvw = (const float*)d_in[3];
  const float* qkvb = (const float*)d_in[4];
  const float* outw = (const float*)d_in[5];
  const float* outb = (const float*)d_in[6];
  const float* fc1w = (const float*)d_in[7];
  const float* fc1b = (const float*)d_in[8];
  const float* fc2w = (const float*)d_in[9];
  const float* fc2b = (const float*)d_in[10];
  float* out = (float*)d_out;

  char* ws = (char*)d_ws;
  size_t off = 0;
  auto alloc = [&](size_t bytes) -> char* {
    char* p = ws + off;
    off += (bytes + 255) & ~(size_t)255;
    return p;
  };
  bf16_t* w1t   = (bf16_t*)alloc((size_t)NA * HID * 2);    // [17920][2560]
  bf16_t* w2t   = (bf16_t*)alloc((size_t)HID * KB * 2);    // [2560][12800]
  bf16_t* ln_out= (bf16_t*)alloc((size_t)ROWS * HID * 2);
  bf16_t* Ubuf  = (bf16_t*)alloc((size_t)ROWS * KB * 2);   // [attn|fc1a]
  bf16_t* q_pad = (bf16_t*)alloc((size_t)BB * NUM_HEADS * SS * DQK * 2);
  bf16_t* k_pad = (bf16_t*)alloc((size_t)BB * NUM_HEADS * SS * DQK * 2);
  bf16_t* v_t   = (bf16_t*)alloc((size_t)BB * NUM_HEADS * HEAD * SS * 2);

  // 1) weights -> bf16 [N][K] fused layouts
  wconv64<<<dim3(H3 / 64, HID / 64), 256, 0, stream>>>(qkvw, w1t, HID, H3, HID);
  wconv64<<<dim3(H4 / 64, HID / 64), 256, 0, stream>>>(fc1w, w1t + (size_t)H3 * HID, HID, H4, HID);
  wconv64<<<dim3(HID / 64, HID / 64), 256, 0, stream>>>(outw, w2t, HID, HID, KB);
  wconv64<<<dim3(HID / 64, H4 / 64), 256, 0, stream>>>(fc2w, w2t + HID, H4, HID, KB);

  // 2) layernorm
  ln_kernel<<<ROWS, 256, 0, stream>>>(hid, lnw, lnb, ln_out);

  // 3) zero q/k pads (cols 80..103 must be 0)
  hipMemsetAsync(q_pad, 0, (size_t)BB * NUM_HEADS * SS * DQK * 2, stream);
  hipMemsetAsync(k_pad, 0, (size_t)BB * NUM_HEADS * SS * DQK * 2, stream);

  // 4) fused QKV+FC1 GEMM
  gemm_bt<0><<<dim3(NA / 128, ROWS / 128), 256, 0, stream>>>(
      ln_out, w1t, ROWS, NA, HID, qkvb, fc1b,
      nullptr, nullptr, Ubuf, q_pad, k_pad, v_t);

  // 5) partial rope
  rope_kernel<<<(BB * NUM_HEADS * SS * 16 * 2) / 256, 256, 0, stream>>>(q_pad, k_pad);

  // 6) causal flash attention -> U[:, 0:2560)
  attn_kernel<<<dim3(SS / 64, NUM_HEADS, BB), 256, 0, stream>>>(q_pad, k_pad, v_t, Ubuf);

  // 7) fused outproj+FC2 GEMM + residual epilogue
  gemm_bt<1><<<dim3(HID / 128, ROWS / 128), 256, 0, stream>>>(
      Ubuf, w2t, ROWS, HID, KB, outb, fc2b,
      hid, out, nullptr, nullptr, nullptr, nullptr);
}